// Round 2
// baseline (357.116 us; speedup 1.0000x reference)
//
#include <hip/hip_runtime.h>
#include <hip/hip_bf16.h>

// Problem constants
#define B_SZ 2
#define LSEQ 1024
#define DIN  2048
#define DST  16
#define DTR  64
#define KTOT 96          // DTR + 2*DST
#define NCH  32          // number of L-chunks
#define TCH  32          // timesteps per chunk (LSEQ / NCH)

// bf16 (as ushort) -> float
__device__ __forceinline__ float b2f(unsigned int u) {
    union { unsigned int i; float f; } v;
    v.i = (u & 0xffffu) << 16;
    return v.f;
}

__device__ __forceinline__ void unpack8(uint4 v, float* f) {
    f[0] = b2f(v.x);        f[1] = b2f(v.x >> 16);
    f[2] = b2f(v.y);        f[3] = b2f(v.y >> 16);
    f[4] = b2f(v.z);        f[5] = b2f(v.z >> 16);
    f[6] = b2f(v.w);        f[7] = b2f(v.w >> 16);
}

// scalar load helper: element i of a buffer that is either fp32 or bf16
__device__ __forceinline__ float ldf(const void* p, size_t i, bool f32) {
    return f32 ? ((const float*)p)[i] : b2f(((const unsigned short*)p)[i]);
}

// ---------------------------------------------------------------------------
// Kernel 0: dtype detector. Samples the LOW ushort of the first 4096 32-bit
// words of x. If x is bf16, those are real bf16 elements of ~N(0,1): |v| in
// [2^-24, 2^24] essentially always. If x is fp32, they are low-mantissa
// noise: exponent uniform => only ~19% land in that range. flag=1 -> fp32.
// ---------------------------------------------------------------------------
__global__ __launch_bounds__(256) void k_detect(const void* __restrict__ x,
                                                int* __restrict__ flag) {
    __shared__ int cnt;
    if (threadIdx.x == 0) cnt = 0;
    __syncthreads();
    const unsigned short* u = (const unsigned short*)x;
    int my = 0;
    for (int i = threadIdx.x; i < 4096; i += 256) {
        unsigned short v = u[2 * i];
        float af = fabsf(b2f(v));
        if (v == 0 || (af >= 6.0e-8f && af <= 1.7e7f)) my++;
    }
    atomicAdd(&cnt, my);
    __syncthreads();
    if (threadIdx.x == 0) *flag = (cnt < 2048) ? 1 : 0;
}

// ---------------------------------------------------------------------------
// Kernel 1: input projection xz = x_row @ Wx^T (96 outputs per (b,l) row).
// Writes delta_raw (fp32) + B_in + C_in to workspace.
// ---------------------------------------------------------------------------
__global__ __launch_bounds__(256) void k_proj(
    const void* __restrict__ x,      // [B][L][DIN]
    const void* __restrict__ Wx,     // [96][DIN]
    const int*  __restrict__ flag,
    float* __restrict__ drw,         // [B][L][DTR]
    float* __restrict__ Bin,         // [B][L][DST]
    float* __restrict__ Cin)         // [B][L][DST]
{
    const bool f32 = (*flag != 0);
    __shared__ float xrow[DIN];
    const int r   = blockIdx.x;      // b*LSEQ + l
    const int tid = threadIdx.x;

    // stage x row into LDS as fp32
    if (f32) {
        const float4* xp = (const float4*)((const float*)x + (size_t)r * DIN);
        float4 a = xp[tid * 2], b = xp[tid * 2 + 1];
        xrow[tid * 8 + 0] = a.x; xrow[tid * 8 + 1] = a.y;
        xrow[tid * 8 + 2] = a.z; xrow[tid * 8 + 3] = a.w;
        xrow[tid * 8 + 4] = b.x; xrow[tid * 8 + 5] = b.y;
        xrow[tid * 8 + 6] = b.z; xrow[tid * 8 + 7] = b.w;
    } else {
        const uint4* xp = (const uint4*)((const unsigned short*)x + (size_t)r * DIN);
        uint4 v = xp[tid];
        float f[8];
        unpack8(v, f);
        #pragma unroll
        for (int j = 0; j < 8; j++) xrow[tid * 8 + j] = f[j];
    }
    __syncthreads();

    // 96 outputs, 2 threads per output (K split in halves)
    if (tid < 2 * KTOT) {
        const int k = tid >> 1, h = tid & 1;
        const size_t off = (size_t)k * DIN + (size_t)h * (DIN / 2);
        const float* xs = xrow + h * (DIN / 2);
        float acc = 0.f;
        if (f32) {
            const float4* w4 = (const float4*)((const float*)Wx + off);
            #pragma unroll 8
            for (int i = 0; i < DIN / 2 / 4; i++) {
                float4 w = w4[i];
                acc += xs[i * 4 + 0] * w.x + xs[i * 4 + 1] * w.y
                     + xs[i * 4 + 2] * w.z + xs[i * 4 + 3] * w.w;
            }
        } else {
            const uint4* w4 = (const uint4*)((const unsigned short*)Wx + off);
            #pragma unroll 4
            for (int i = 0; i < DIN / 2 / 8; i++) {
                float f[8];
                unpack8(w4[i], f);
                #pragma unroll
                for (int j = 0; j < 8; j++) acc += xs[i * 8 + j] * f[j];
            }
        }
        acc += __shfl_xor(acc, 1, 64);   // combine halves (adjacent lanes)
        if (h == 0) {
            if (k < DTR)            drw[(size_t)r * DTR + k] = acc;
            else if (k < DTR + DST) Bin[(size_t)r * DST + (k - DTR)] = acc;
            else                    Cin[(size_t)r * DST + (k - DTR - DST)] = acc;
        }
    }
}

// ---------------------------------------------------------------------------
// Shared scan-body helper pieces are inlined in scan1/scan3; dt is recomputed
// identically in both: dt = softplus(delta_raw . Wdt_row + bdt[d]).
// ---------------------------------------------------------------------------

// Kernel 2 (scan phase 1): per (b, chunk, d) chunk-local scan with h0=0:
//   P[s] = prod_t exp(dt*A[s]),  H[s] = end state.
__global__ __launch_bounds__(256) void k_scan1(
    const void* __restrict__ x,
    const void* __restrict__ Wdt,    // [DIN][DTR]
    const void* __restrict__ bdt,    // [DIN]
    const void* __restrict__ Alog,   // [DIN][DST]
    const float* __restrict__ drw,
    const float* __restrict__ Bin,
    const int*  __restrict__ flag,
    float* __restrict__ Pb,          // [B][NCH][DST][DIN]
    float* __restrict__ Hb)          // [B][NCH][DST][DIN]
{
    const bool f32 = (*flag != 0);
    __shared__ float drL[TCH * DTR];   // 8 KB
    __shared__ float Bs[TCH * DST];    // 2 KB
    const int tid = threadIdx.x;
    const int d = blockIdx.x * 256 + tid;
    const int c = blockIdx.y;
    const int b = blockIdx.z;
    const int row0 = b * LSEQ + c * TCH;

    for (int i = tid; i < TCH * DTR; i += 256) drL[i] = drw[(size_t)row0 * DTR + i];
    for (int i = tid; i < TCH * DST; i += 256) Bs[i]  = Bin[(size_t)row0 * DST + i];

    // per-thread Wdt row, bias, A
    float w[DTR];
    if (f32) {
        const float* wp = (const float*)Wdt + (size_t)d * DTR;
        #pragma unroll
        for (int j = 0; j < DTR; j++) w[j] = wp[j];
    } else {
        const uint4* wp = (const uint4*)((const unsigned short*)Wdt + (size_t)d * DTR);
        #pragma unroll
        for (int i = 0; i < DTR / 8; i++) unpack8(wp[i], w + i * 8);
    }
    const float bd = ldf(bdt, d, f32);
    float A[DST];
    #pragma unroll
    for (int s = 0; s < DST; s++) A[s] = -__expf(ldf(Alog, (size_t)d * DST + s, f32));
    __syncthreads();

    float P[DST], H[DST];
    #pragma unroll
    for (int s = 0; s < DST; s++) { P[s] = 1.f; H[s] = 0.f; }

    for (int t = 0; t < TCH; t++) {
        const float* dr = drL + t * DTR;
        float acc = bd;
        #pragma unroll
        for (int j = 0; j < DTR; j++) acc += w[j] * dr[j];
        const float dtv = (acc > 20.f) ? acc : log1pf(__expf(acc));
        const float xv = ldf(x, (size_t)(row0 + t) * DIN + d, f32);
        const float u = dtv * xv;
        const float* bs = Bs + t * DST;
        #pragma unroll
        for (int s = 0; s < DST; s++) {
            const float e = __expf(dtv * A[s]);
            P[s] *= e;
            H[s] = e * H[s] + u * bs[s];
        }
    }

    const size_t base = (size_t)(b * NCH + c) * DST * DIN + d;
    #pragma unroll
    for (int s = 0; s < DST; s++) {
        Pb[base + (size_t)s * DIN] = P[s];
        Hb[base + (size_t)s * DIN] = H[s];
    }
}

// Kernel 3 (scan phase 2): cross-chunk exclusive scan per (b,s,d).
// IN-PLACE: Pb is overwritten with hin[c] (state entering chunk c).
__global__ __launch_bounds__(256) void k_scan2(
    float* __restrict__ Pb,
    const float* __restrict__ Hb)
{
    const int idx = blockIdx.x * 256 + threadIdx.x;   // b*(DST*DIN) + rem
    const int b   = idx / (DST * DIN);
    const int rem = idx % (DST * DIN);
    float h = 0.f;
    for (int c = 0; c < NCH; c++) {
        const size_t o = (size_t)(b * NCH + c) * DST * DIN + rem;
        const float p = Pb[o], hb = Hb[o];
        Pb[o] = h;                 // hin for chunk c (safe: already read p)
        h = hb + p * h;
    }
}

// Kernel 4 (scan phase 3): rerun local scan seeded with hin(=Pb), emit y.
__global__ __launch_bounds__(256) void k_scan3(
    const void* __restrict__ x,
    const void* __restrict__ Wdt,
    const void* __restrict__ bdt,
    const void* __restrict__ Alog,
    const void* __restrict__ Dv,     // [DIN]
    const float* __restrict__ drw,
    const float* __restrict__ Bin,
    const float* __restrict__ Cin,
    const float* __restrict__ hin,   // = Pb after k_scan2
    const int*  __restrict__ flag,
    void* __restrict__ y)            // [B][L][DIN], fp32 or bf16 per flag
{
    const bool f32 = (*flag != 0);
    __shared__ float drL[TCH * DTR];
    __shared__ float Bs[TCH * DST];
    __shared__ float Cs[TCH * DST];
    const int tid = threadIdx.x;
    const int d = blockIdx.x * 256 + tid;
    const int c = blockIdx.y;
    const int b = blockIdx.z;
    const int row0 = b * LSEQ + c * TCH;

    for (int i = tid; i < TCH * DTR; i += 256) drL[i] = drw[(size_t)row0 * DTR + i];
    for (int i = tid; i < TCH * DST; i += 256) {
        Bs[i] = Bin[(size_t)row0 * DST + i];
        Cs[i] = Cin[(size_t)row0 * DST + i];
    }

    float w[DTR];
    if (f32) {
        const float* wp = (const float*)Wdt + (size_t)d * DTR;
        #pragma unroll
        for (int j = 0; j < DTR; j++) w[j] = wp[j];
    } else {
        const uint4* wp = (const uint4*)((const unsigned short*)Wdt + (size_t)d * DTR);
        #pragma unroll
        for (int i = 0; i < DTR / 8; i++) unpack8(wp[i], w + i * 8);
    }
    const float bd = ldf(bdt, d, f32);
    const float Dd = ldf(Dv, d, f32);
    float A[DST];
    #pragma unroll
    for (int s = 0; s < DST; s++) A[s] = -__expf(ldf(Alog, (size_t)d * DST + s, f32));
    __syncthreads();

    float h[DST];
    const size_t base = (size_t)(b * NCH + c) * DST * DIN + d;
    #pragma unroll
    for (int s = 0; s < DST; s++) h[s] = hin[base + (size_t)s * DIN];

    for (int t = 0; t < TCH; t++) {
        const float* dr = drL + t * DTR;
        float acc = bd;
        #pragma unroll
        for (int j = 0; j < DTR; j++) acc += w[j] * dr[j];
        const float dtv = (acc > 20.f) ? acc : log1pf(__expf(acc));
        const size_t off = (size_t)(row0 + t) * DIN + d;
        const float xv = ldf(x, off, f32);
        const float u = dtv * xv;
        const float* bs = Bs + t * DST;
        const float* cs = Cs + t * DST;
        float yv = Dd * xv;
        #pragma unroll
        for (int s = 0; s < DST; s++) {
            const float e = __expf(dtv * A[s]);
            h[s] = e * h[s] + u * bs[s];
            yv += h[s] * cs[s];
        }
        if (f32) ((float*)y)[off] = yv;
        else     ((__hip_bfloat16*)y)[off] = __float2bfloat16(yv);
    }
}

// ---------------------------------------------------------------------------
extern "C" void kernel_launch(void* const* d_in, const int* in_sizes, int n_in,
                              void* d_out, int out_size, void* d_ws, size_t ws_size,
                              hipStream_t stream) {
    const void* x    = d_in[0];
    const void* Wx   = d_in[1];
    const void* Wdt  = d_in[2];
    const void* bdt  = d_in[3];
    const void* Alog = d_in[4];
    const void* Dv   = d_in[5];

    // workspace carve-up (~16.9 MB)
    int*   flag = (int*)d_ws;
    float* base = (float*)d_ws + 16;                       // 64B offset, aligned
    float* drw  = base;                                    // B*L*DTR  = 131072
    float* Bin  = drw + (size_t)B_SZ * LSEQ * DTR;         // B*L*DST  = 32768
    float* Cin  = Bin + (size_t)B_SZ * LSEQ * DST;         // B*L*DST  = 32768
    float* Pb   = Cin + (size_t)B_SZ * LSEQ * DST;         // B*NCH*DST*DIN = 2097152
    float* Hb   = Pb  + (size_t)B_SZ * NCH * DST * DIN;    // 2097152

    k_detect<<<1, 256, 0, stream>>>(x, flag);

    k_proj<<<B_SZ * LSEQ, 256, 0, stream>>>(x, Wx, flag, drw, Bin, Cin);

    dim3 g1(DIN / 256, NCH, B_SZ);
    k_scan1<<<g1, 256, 0, stream>>>(x, Wdt, bdt, Alog, drw, Bin, flag, Pb, Hb);

    k_scan2<<<(B_SZ * DST * DIN) / 256, 256, 0, stream>>>(Pb, Hb);

    k_scan3<<<g1, 256, 0, stream>>>(x, Wdt, bdt, Alog, Dv, drw, Bin, Cin,
                                    Pb, flag, d_out);
}

// Round 3
// 189.018 us; speedup vs baseline: 1.8893x; 1.8893x over previous
//
#include <hip/hip_runtime.h>
#include <hip/hip_bf16.h>

// Problem constants
#define B_SZ 2
#define LSEQ 1024
#define DIN  2048
#define DST  16
#define DTR  64
#define KTOT 96          // DTR + 2*DST
#define NROW (B_SZ * LSEQ)   // 2048 (b,l) rows
#define NCH  32          // number of L-chunks
#define TCH  32          // timesteps per chunk
#define KSP  32          // K-splits in k_proj (64 K each)

// bf16 (as ushort) -> float
__device__ __forceinline__ float b2f(unsigned int u) {
    union { unsigned int i; float f; } v;
    v.i = (u & 0xffffu) << 16;
    return v.f;
}

// scalar load: element i of a buffer that is either fp32 or bf16
__device__ __forceinline__ float ldf(const void* p, size_t i, bool f32) {
    return f32 ? ((const float*)p)[i] : b2f(((const unsigned short*)p)[i]);
}

// 4 consecutive elements as float4, dual dtype
__device__ __forceinline__ float4 ld4(const void* p, size_t i, bool f32) {
    if (f32) return *(const float4*)((const float*)p + i);
    const uint2 u = *(const uint2*)((const unsigned short*)p + i);
    float4 v;
    v.x = b2f(u.x); v.y = b2f(u.x >> 16);
    v.z = b2f(u.y); v.w = b2f(u.y >> 16);
    return v;
}

__device__ __forceinline__ float softplus_f(float v) {
    return (v > 20.f) ? v : log1pf(__expf(v));
}

// ---------------------------------------------------------------------------
// Kernel 0: dtype detector (unchanged from round 2 — it worked; picked fp32).
// flag=1 -> fp32, flag=0 -> bf16.
// ---------------------------------------------------------------------------
__global__ __launch_bounds__(256) void k_detect(const void* __restrict__ x,
                                                int* __restrict__ flag) {
    __shared__ int cnt;
    if (threadIdx.x == 0) cnt = 0;
    __syncthreads();
    const unsigned short* u = (const unsigned short*)x;
    int my = 0;
    for (int i = threadIdx.x; i < 4096; i += 256) {
        unsigned short v = u[2 * i];
        float af = fabsf(b2f(v));
        if (v == 0 || (af >= 6.0e-8f && af <= 1.7e7f)) my++;
    }
    atomicAdd(&cnt, my);
    __syncthreads();
    if (threadIdx.x == 0) *flag = (cnt < 2048) ? 1 : 0;
}

// ---------------------------------------------------------------------------
// Kernel 1: input projection as a tiled split-K GEMM.
// C[2048 rows][96] = x[2048][2048] . Wx^T[2048][96]
// Block: 192 threads, tile 128 rows x 96 cols, K-slice of 64 (2 sub-chunks
// of 32 staged in LDS K-major), thread-tile 8x8 (64 accumulators).
// Writes partial tile to part[ksplit][row][96].
// ---------------------------------------------------------------------------
__global__ __launch_bounds__(192) void k_proj(
    const void* __restrict__ x,      // [NROW][DIN]
    const void* __restrict__ Wx,     // [96][DIN]
    const int*  __restrict__ flag,
    float* __restrict__ part)        // [KSP][NROW][96]
{
    const bool f32 = (*flag != 0);
    __shared__ float lx[32][132];    // [k][row], padded
    __shared__ float lw[32][100];    // [k][col], padded
    const int tid = threadIdx.x;
    const int bx = blockIdx.x;       // row group (128 rows)
    const int by = blockIdx.y;       // K-split (64 K)
    const int rt = tid / 12, ct = tid % 12;
    const int r0 = rt * 8, c0 = ct * 8;

    float acc[8][8];
    #pragma unroll
    for (int i = 0; i < 8; i++)
        #pragma unroll
        for (int k = 0; k < 8; k++) acc[i][k] = 0.f;

    for (int half = 0; half < 2; half++) {
        const int k0 = by * 64 + half * 32;
        // stage x tile: 128 rows x 32 k (transposed into LDS)
        for (int idx = tid; idx < 1024; idx += 192) {
            const int r = idx >> 3, q = idx & 7;
            const size_t g = (size_t)(bx * 128 + r) * DIN + k0 + q * 4;
            float4 v = ld4(x, g, f32);
            lx[q * 4 + 0][r] = v.x; lx[q * 4 + 1][r] = v.y;
            lx[q * 4 + 2][r] = v.z; lx[q * 4 + 3][r] = v.w;
        }
        // stage w tile: 96 cols x 32 k
        for (int idx = tid; idx < 768; idx += 192) {
            const int c = idx >> 3, q = idx & 7;
            const size_t g = (size_t)c * DIN + k0 + q * 4;
            float4 v = ld4(Wx, g, f32);
            lw[q * 4 + 0][c] = v.x; lw[q * 4 + 1][c] = v.y;
            lw[q * 4 + 2][c] = v.z; lw[q * 4 + 3][c] = v.w;
        }
        __syncthreads();

        for (int j = 0; j < 32; j++) {
            const float4 xa = *(const float4*)&lx[j][r0];
            const float4 xb = *(const float4*)&lx[j][r0 + 4];
            const float4 wa = *(const float4*)&lw[j][c0];
            const float4 wb = *(const float4*)&lw[j][c0 + 4];
            const float xr[8] = {xa.x, xa.y, xa.z, xa.w, xb.x, xb.y, xb.z, xb.w};
            const float wc[8] = {wa.x, wa.y, wa.z, wa.w, wb.x, wb.y, wb.z, wb.w};
            #pragma unroll
            for (int i = 0; i < 8; i++)
                #pragma unroll
                for (int k = 0; k < 8; k++)
                    acc[i][k] += xr[i] * wc[k];
        }
        __syncthreads();
    }

    // write partial tile (no collisions: unique (by, bx, r, c) per thread)
    float* p = part + (size_t)by * NROW * KTOT + (size_t)(bx * 128) * KTOT;
    #pragma unroll
    for (int i = 0; i < 8; i++) {
        float* row = p + (size_t)(r0 + i) * KTOT + c0;
        *(float4*)(row)     = make_float4(acc[i][0], acc[i][1], acc[i][2], acc[i][3]);
        *(float4*)(row + 4) = make_float4(acc[i][4], acc[i][5], acc[i][6], acc[i][7]);
    }
}

// ---------------------------------------------------------------------------
// Kernel 2: combine K-split partials -> drw / Bin / Cin (deterministic).
// ---------------------------------------------------------------------------
__global__ __launch_bounds__(256) void k_comb(
    const float* __restrict__ part,
    float* __restrict__ drw, float* __restrict__ Bin, float* __restrict__ Cin)
{
    const int idx = blockIdx.x * 256 + threadIdx.x;   // < NROW*96
    float s = 0.f;
    #pragma unroll 8
    for (int ks = 0; ks < KSP; ks++)
        s += part[(size_t)ks * NROW * KTOT + idx];
    const int r = idx / KTOT, c = idx % KTOT;
    if (c < DTR)            drw[r * DTR + c] = s;
    else if (c < DTR + DST) Bin[r * DST + (c - DTR)] = s;
    else                    Cin[r * DST + (c - DTR - DST)] = s;
}

// ---------------------------------------------------------------------------
// Kernel 3: dt GEMM + softplus.  dt[r][d] = softplus(drw[r][:] . Wdt[d][:] + bdt[d])
// M=2048, N=2048, K=64 (single LDS stage). Block 256, tile 64x64, thread 4x4.
// ---------------------------------------------------------------------------
__global__ __launch_bounds__(256) void k_dt(
    const float* __restrict__ drw,   // [NROW][DTR]
    const void* __restrict__ Wdt,    // [DIN][DTR]
    const void* __restrict__ bdt,    // [DIN]
    const int*  __restrict__ flag,
    float* __restrict__ dt)          // [NROW][DIN]
{
    const bool f32 = (*flag != 0);
    __shared__ float la[64][68];     // [k][row]
    __shared__ float lb[64][68];     // [k][col]
    const int tid = threadIdx.x;
    const int r0g = blockIdx.x * 64, c0g = blockIdx.y * 64;

    for (int idx = tid; idx < 1024; idx += 256) {
        const int r = idx >> 4, q = idx & 15;
        float4 v = *(const float4*)(drw + (size_t)(r0g + r) * DTR + q * 4);
        la[q * 4 + 0][r] = v.x; la[q * 4 + 1][r] = v.y;
        la[q * 4 + 2][r] = v.z; la[q * 4 + 3][r] = v.w;
    }
    for (int idx = tid; idx < 1024; idx += 256) {
        const int c = idx >> 4, q = idx & 15;
        float4 v = ld4(Wdt, (size_t)(c0g + c) * DTR + q * 4, f32);
        lb[q * 4 + 0][c] = v.x; lb[q * 4 + 1][c] = v.y;
        lb[q * 4 + 2][c] = v.z; lb[q * 4 + 3][c] = v.w;
    }
    __syncthreads();

    const int rt = tid >> 4, ct = tid & 15;
    const int r0 = rt * 4, c0 = ct * 4;
    float acc[4][4];
    #pragma unroll
    for (int i = 0; i < 4; i++)
        #pragma unroll
        for (int k = 0; k < 4; k++) acc[i][k] = 0.f;

    for (int j = 0; j < 64; j++) {
        const float4 a = *(const float4*)&la[j][r0];
        const float4 b = *(const float4*)&lb[j][c0];
        const float ar[4] = {a.x, a.y, a.z, a.w};
        const float bc[4] = {b.x, b.y, b.z, b.w};
        #pragma unroll
        for (int i = 0; i < 4; i++)
            #pragma unroll
            for (int k = 0; k < 4; k++)
                acc[i][k] += ar[i] * bc[k];
    }

    float bd[4];
    #pragma unroll
    for (int k = 0; k < 4; k++) bd[k] = ldf(bdt, (size_t)(c0g + c0 + k), f32);
    #pragma unroll
    for (int i = 0; i < 4; i++) {
        float4 o;
        o.x = softplus_f(acc[i][0] + bd[0]);
        o.y = softplus_f(acc[i][1] + bd[1]);
        o.z = softplus_f(acc[i][2] + bd[2]);
        o.w = softplus_f(acc[i][3] + bd[3]);
        *(float4*)(dt + (size_t)(r0g + r0 + i) * DIN + c0g + c0) = o;
    }
}

// ---------------------------------------------------------------------------
// Kernel 4 (scan phase 1): per (b, chunk, d) chunk-local scan, h0=0.
//   P[s] = prod_t exp(dt*A[s]),  H[s] = end state.
// ---------------------------------------------------------------------------
__global__ __launch_bounds__(256) void k_scan1(
    const void* __restrict__ x,
    const float* __restrict__ dt,
    const float* __restrict__ Bin,
    const void* __restrict__ Alog,
    const int*  __restrict__ flag,
    float* __restrict__ Pb,          // [B][NCH][DST][DIN]
    float* __restrict__ Hb)
{
    const bool f32 = (*flag != 0);
    __shared__ float Bs[TCH * DST];
    const int tid = threadIdx.x;
    const int d = blockIdx.x * 256 + tid;
    const int c = blockIdx.y;
    const int b = blockIdx.z;
    const int row0 = b * LSEQ + c * TCH;

    for (int i = tid; i < TCH * DST; i += 256) Bs[i] = Bin[(size_t)row0 * DST + i];

    float A[DST];
    #pragma unroll
    for (int s = 0; s < DST; s++) A[s] = -__expf(ldf(Alog, (size_t)d * DST + s, f32));
    __syncthreads();

    float P[DST], H[DST];
    #pragma unroll
    for (int s = 0; s < DST; s++) { P[s] = 1.f; H[s] = 0.f; }

    #pragma unroll 4
    for (int t = 0; t < TCH; t++) {
        const size_t off = (size_t)(row0 + t) * DIN + d;
        const float dtv = dt[off];
        const float xv  = ldf(x, off, f32);
        const float u   = dtv * xv;
        const float* bs = Bs + t * DST;
        #pragma unroll
        for (int s = 0; s < DST; s++) {
            const float e = __expf(dtv * A[s]);
            P[s] *= e;
            H[s] = e * H[s] + u * bs[s];
        }
    }

    const size_t base = (size_t)(b * NCH + c) * DST * DIN + d;
    #pragma unroll
    for (int s = 0; s < DST; s++) {
        Pb[base + (size_t)s * DIN] = P[s];
        Hb[base + (size_t)s * DIN] = H[s];
    }
}

// ---------------------------------------------------------------------------
// Kernel 5 (scan phase 2): cross-chunk exclusive scan per (b,s,d).
// IN-PLACE: Pb becomes hin[c] (state entering chunk c).
// ---------------------------------------------------------------------------
__global__ __launch_bounds__(256) void k_scan2(
    float* __restrict__ Pb,
    const float* __restrict__ Hb)
{
    const int idx = blockIdx.x * 256 + threadIdx.x;
    const int b   = idx / (DST * DIN);
    const int rem = idx % (DST * DIN);
    float h = 0.f;
    for (int c = 0; c < NCH; c++) {
        const size_t o = (size_t)(b * NCH + c) * DST * DIN + rem;
        const float p = Pb[o], hb = Hb[o];
        Pb[o] = h;
        h = hb + p * h;
    }
}

// ---------------------------------------------------------------------------
// Kernel 6 (scan phase 3): local scan seeded with hin, emit y.
// ---------------------------------------------------------------------------
__global__ __launch_bounds__(256) void k_scan3(
    const void* __restrict__ x,
    const float* __restrict__ dt,
    const float* __restrict__ Bin,
    const float* __restrict__ Cin,
    const void* __restrict__ Alog,
    const void* __restrict__ Dv,
    const float* __restrict__ hin,   // = Pb after k_scan2
    const int*  __restrict__ flag,
    void* __restrict__ y)
{
    const bool f32 = (*flag != 0);
    __shared__ float Bs[TCH * DST];
    __shared__ float Cs[TCH * DST];
    const int tid = threadIdx.x;
    const int d = blockIdx.x * 256 + tid;
    const int c = blockIdx.y;
    const int b = blockIdx.z;
    const int row0 = b * LSEQ + c * TCH;

    for (int i = tid; i < TCH * DST; i += 256) {
        Bs[i] = Bin[(size_t)row0 * DST + i];
        Cs[i] = Cin[(size_t)row0 * DST + i];
    }

    float A[DST];
    #pragma unroll
    for (int s = 0; s < DST; s++) A[s] = -__expf(ldf(Alog, (size_t)d * DST + s, f32));
    const float Dd = ldf(Dv, d, f32);
    __syncthreads();

    float h[DST];
    const size_t base = (size_t)(b * NCH + c) * DST * DIN + d;
    #pragma unroll
    for (int s = 0; s < DST; s++) h[s] = hin[base + (size_t)s * DIN];

    #pragma unroll 4
    for (int t = 0; t < TCH; t++) {
        const size_t off = (size_t)(row0 + t) * DIN + d;
        const float dtv = dt[off];
        const float xv  = ldf(x, off, f32);
        const float u   = dtv * xv;
        const float* bs = Bs + t * DST;
        const float* cs = Cs + t * DST;
        float yv = Dd * xv;
        #pragma unroll
        for (int s = 0; s < DST; s++) {
            const float e = __expf(dtv * A[s]);
            h[s] = e * h[s] + u * bs[s];
            yv += h[s] * cs[s];
        }
        if (f32) ((float*)y)[off] = yv;
        else     ((__hip_bfloat16*)y)[off] = __float2bfloat16(yv);
    }
}

// ---------------------------------------------------------------------------
extern "C" void kernel_launch(void* const* d_in, const int* in_sizes, int n_in,
                              void* d_out, int out_size, void* d_ws, size_t ws_size,
                              hipStream_t stream) {
    const void* x    = d_in[0];
    const void* Wx   = d_in[1];
    const void* Wdt  = d_in[2];
    const void* bdt  = d_in[3];
    const void* Alog = d_in[4];
    const void* Dv   = d_in[5];

    // ---- workspace layout (~34.4 MB) ----
    // [flag | drw | Bin | Cin | big]
    //   big aliases: phase A: part (KSP*NROW*96 = 6.29M floats)
    //                phase B: dt (4.19M) + Pb (2.10M) + Hb (2.10M)
    // part is dead after k_comb, before k_dt writes dt.
    int*   flag = (int*)d_ws;
    float* basep = (float*)d_ws + 16;
    float* drw  = basep;                                   // NROW*DTR
    float* Bin  = drw + (size_t)NROW * DTR;                // NROW*DST
    float* Cin  = Bin + (size_t)NROW * DST;                // NROW*DST
    float* big  = Cin + (size_t)NROW * DST;
    float* part = big;                                     // 6,291,456 floats
    float* dt   = big;                                     // 4,194,304 floats
    float* Pb   = dt + (size_t)NROW * DIN;                 // 2,097,152
    float* Hb   = Pb + (size_t)B_SZ * NCH * DST * DIN;     // 2,097,152

    k_detect<<<1, 256, 0, stream>>>(x, flag);

    k_proj<<<dim3(NROW / 128, KSP), 192, 0, stream>>>(x, Wx, flag, part);

    k_comb<<<(NROW * KTOT) / 256, 256, 0, stream>>>(part, drw, Bin, Cin);

    k_dt<<<dim3(NROW / 64, DIN / 64), 256, 0, stream>>>(drw, Wdt, bdt, flag, dt);

    dim3 g1(DIN / 256, NCH, B_SZ);
    k_scan1<<<g1, 256, 0, stream>>>(x, dt, Bin, Alog, flag, Pb, Hb);

    k_scan2<<<(B_SZ * DST * DIN) / 256, 256, 0, stream>>>(Pb, Hb);

    k_scan3<<<g1, 256, 0, stream>>>(x, dt, Bin, Cin, Alog, Dv, Pb, flag, d_out);
}